// Round 15
// baseline (165.432 us; speedup 1.0000x reference)
//
#include <hip/hip_runtime.h>
#include <math.h>

// Problem dims (from reference): B=4, C=64, T=16, H=128, W=128, fp32.
#define BB 4
#define CC 64
#define TT 16
#define HH 128
#define WW 128
#define HW (HH*WW)

typedef float f32x4 __attribute__((ext_vector_type(4)));

__device__ __forceinline__ float softplus_f(float x) {
    return (x > 20.0f) ? x : log1pf(expf(x));
}

__device__ __forceinline__ float4 splat4(float v) { return make_float4(v, v, v, v); }

// float4 cross-lane fetch within a 32-lane row segment (ds_bpermute x4).
__device__ __forceinline__ float4 shfl4(float4 v, int src) {
    float4 r;
    r.x = __shfl(v.x, src, 32);
    r.y = __shfl(v.y, src, 32);
    r.z = __shfl(v.z, src, 32);
    r.w = __shfl(v.w, src, 32);
    return r;
}

// lgkm-only barrier (no vmcnt drain -- round-5 proof). Here it is a cheap
// plane-boundary sync: shuffles are already consumed, so lgkmcnt(0) is
// nearly free, and global loads/NT-stores stay in flight across it.
__device__ __forceinline__ void barrier_lgkm() {
    asm volatile("s_waitcnt lgkmcnt(0)\n\ts_barrier" ::: "memory");
}

// Round-11 body (101us best) with the FETCH-thrash fix. Evidence across
// rounds 11-14: dur tracks FETCH_SIZE monotonically; the extra fetches are
// d=+-16 taps into SIBLING bands that miss L2 when bands desync in t
// (XCD L2 = 4MB holds ~32 stacks x 1 plane = 2MB; desync doubles that).
// Fix: ONE 1024-thread block per (b,c) stack (256 blocks, 1 per CU) so all
// taps are intra-block, plus one lgkm-only s_barrier per plane keeping the
// block's 16 waves plane-locked -> per-XCD working set 32 stacks x ~1 plane
// = 2MB <= 4MB L2 -> every tap is an L2 hit (~200cyc) instead of HBM
// (~900cyc).
//  - NO LDS buffers; horizontal taps via lane shuffles (round-11 win)
//  - thread owns 4 stacked rows: d=1 vertical taps from own registers
//  - temporal history (t-1, t-2) in registers -> temporal taps free
//  - NT stores: output never re-read, keep L2 for u
//  - plain __launch_bounds__(1024): ",N" variants pinned VGPR and spilled
__global__ __launch_bounds__(1024) void lap_st_kernel(
    const float* __restrict__ u,
    const float* __restrict__ Ds,   // (3, 64)
    const float* __restrict__ Dt,   // (2, 64)
    float* __restrict__ out)
{
    const int bc   = blockIdx.x;           // b*C + c (stack id)
    const int c    = bc & (CC - 1);
    const int tid  = threadIdx.x;
    const int jj   = tid >> 5;             // 0..31 : row group
    const int colc = tid & 31;             // chunk column (lane in row segment)
    const int col  = colc << 2;
    const int r0   = jj << 2;              // first of 4 owned rows, 0..124

    const float cs0 = softplus_f(Ds[0 * CC + c]);
    const float cs1 = softplus_f(Ds[1 * CC + c]);
    const float cs2 = softplus_f(Ds[2 * CC + c]);
    const float ct0 = softplus_f(Dt[0 * CC + c]);
    const float ct1 = softplus_f(Dt[1 * CC + c]);
    const float cu = -4.0f * (cs0 + cs1 + cs2) - (ct0 + ct1);

    const size_t bc_off = (size_t)bc * TT * HW;

    float4 pm1[4], pm2[4];

    #pragma unroll 1
    for (int t = 0; t < TT; ++t) {
        const float* __restrict__ up = u + bc_off + (size_t)t * HW;
        f32x4* outp = (f32x4*)(out + bc_off + (size_t)t * HW);

        // keep all 16 waves on the same plane -> taps stay L2-resident
        barrier_lgkm();

        // center rows (registers; feed +-1 taps, horizontals via shuffle,
        // and the temporal rotate)
        float4 c0[4];
        #pragma unroll
        for (int q = 0; q < 4; ++q)
            c0[q] = *(const float4*)(up + (r0 + q) * WW + col);

        if (t == 0) {   // causal clamp: u[-1] = u[-2] = u[0]
            #pragma unroll
            for (int q = 0; q < 4; ++q) { pm1[q] = c0[q]; pm2[q] = c0[q]; }
        }

        // shared boundary rows (serve +-1 taps of edge q and +-4 taps)
        const int rm1 = (r0 - 1 < 0) ? 0 : r0 - 1;
        const int rp4 = (r0 + 4 > HH - 1) ? HH - 1 : r0 + 4;
        const float4 vm1 = *(const float4*)(up + rm1 * WW + col);
        const float4 vp4 = *(const float4*)(up + rp4 * WW + col);

        #pragma unroll
        for (int q = 0; q < 4; ++q) {
            const int r = r0 + q;

            // ---- vertical taps (register reuse for d=1; clamped loads) ----
            const float4 vu1 = (q == 0) ? vm1 : c0[q - 1];
            const float4 vd1 = (q == 3) ? vp4 : c0[q + 1];
            float4 vu4, vd4;
            if (q == 3) vu4 = vm1;                       // r-4 == r0-1
            else { int rr = r - 4; rr = rr < 0 ? 0 : rr;
                   vu4 = *(const float4*)(up + rr * WW + col); }
            if (q == 0) vd4 = vp4;                       // r+4 == r0+4
            else { int rr = r + 4; rr = rr > HH - 1 ? HH - 1 : rr;
                   vd4 = *(const float4*)(up + rr * WW + col); }
            int ru16 = r - 16; ru16 = ru16 < 0 ? 0 : ru16;
            int rd16 = r + 16; rd16 = rd16 > HH - 1 ? HH - 1 : rd16;
            const float4 vu16 = *(const float4*)(up + ru16 * WW + col);
            const float4 vd16 = *(const float4*)(up + rd16 * WW + col);

            const float4 cc = c0[q];

            // ---- horizontal taps from adjacent lanes' registers ----
            const float4 L4  = shfl4(cc, colc - 1);
            const float4 R4  = shfl4(cc, colc + 1);
            const float4 L16 = shfl4(cc, colc - 4);
            const float4 R16 = shfl4(cc, colc + 4);
            const float e0   = __shfl(cc.x, 0, 32);    // row elem 0
            const float e127 = __shfl(cc.w, 31, 32);   // row elem 127
            const float4 l4  = (colc >= 1)  ? L4  : splat4(e0);
            const float4 r4  = (colc <= 30) ? R4  : splat4(e127);
            const float4 l16 = (colc >= 4)  ? L16 : splat4(e0);
            const float4 r16 = (colc <= 27) ? R16 : splat4(e127);

            const float4 p1 = pm1[q];
            const float4 p2 = pm2[q];

            f32x4 o;
            o.x = cs0 * (vu1.x + vd1.x + l4.w + cc.y)
                + cs1 * (vu4.x + vd4.x + l4.x + r4.x)
                + cs2 * (vu16.x + vd16.x + l16.x + r16.x)
                + cu * cc.x + ct0 * p1.x + ct1 * p2.x;
            o.y = cs0 * (vu1.y + vd1.y + cc.x + cc.z)
                + cs1 * (vu4.y + vd4.y + l4.y + r4.y)
                + cs2 * (vu16.y + vd16.y + l16.y + r16.y)
                + cu * cc.y + ct0 * p1.y + ct1 * p2.y;
            o.z = cs0 * (vu1.z + vd1.z + cc.y + cc.w)
                + cs1 * (vu4.z + vd4.z + l4.z + r4.z)
                + cs2 * (vu16.z + vd16.z + l16.z + r16.z)
                + cu * cc.z + ct0 * p1.z + ct1 * p2.z;
            o.w = cs0 * (vu1.w + vd1.w + cc.z + r4.x)
                + cs1 * (vu4.w + vd4.w + l4.w + r4.w)
                + cs2 * (vu16.w + vd16.w + l16.w + r16.w)
                + cu * cc.w + ct0 * p1.w + ct1 * p2.w;

            __builtin_nontemporal_store(o, &outp[r * 32 + colc]);
        }

        // rotate temporal history
        #pragma unroll
        for (int q = 0; q < 4; ++q) { pm2[q] = pm1[q]; pm1[q] = c0[q]; }
    }
}

extern "C" void kernel_launch(void* const* d_in, const int* in_sizes, int n_in,
                              void* d_out, int out_size, void* d_ws, size_t ws_size,
                              hipStream_t stream) {
    const float* u  = (const float*)d_in[0];
    const float* Ds = (const float*)d_in[1];
    const float* Dt = (const float*)d_in[2];
    float* out = (float*)d_out;

    const int nblocks = BB * CC;   // 256 -> one stack per block, one block per CU
    lap_st_kernel<<<dim3(nblocks), dim3(1024), 0, stream>>>(u, Ds, Dt, out);
}

// Round 16
// 138.035 us; speedup vs baseline: 1.1985x; 1.1985x over previous
//
#include <hip/hip_runtime.h>
#include <math.h>

// Problem dims (from reference): B=4, C=64, T=16, H=128, W=128, fp32.
#define BB 4
#define CC 64
#define TT 16
#define HH 128
#define WW 128
#define HW (HH*WW)

typedef float f32x4 __attribute__((ext_vector_type(4)));

__device__ __forceinline__ float softplus_f(float x) {
    return (x > 20.0f) ? x : log1pf(expf(x));
}

__device__ __forceinline__ float4 splat4(float v) { return make_float4(v, v, v, v); }

// float4 cross-lane fetch within a 32-lane row segment (ds_bpermute x4).
__device__ __forceinline__ float4 shfl4(float4 v, int src) {
    float4 r;
    r.x = __shfl(v.x, src, 32);
    r.y = __shfl(v.y, src, 32);
    r.z = __shfl(v.z, src, 32);
    r.w = __shfl(v.w, src, 32);
    return r;
}

// Round-11 shape EXACTLY (101us best: 1024 blocks x 256 thr, 4-row threads,
// shuffle horizontals, no LDS, no barriers, free-running waves) with one
// change: WITHIN-PLANE LOAD BATCHING. All 20 tap loads of a plane are
// issued into registers before any compute, raising per-wave outstanding
// VMEM from ~6 to ~20 (16 waves/CU x 20 = 320 outstanding) to saturate the
// HBM/L2 stream. This does NOT change grid, stream count, or the temporal
// working-set window -- the proven failure axes of rounds 12/13/14/15
// (more blocks / cross-plane prefetch / wider blocks / barrier lockstep
// all inflated FETCH and regressed; dur tracks FETCH monotonically).
//  - block (sh 0..3, bc) owns rows [32sh,32sh+32) of stack bc for all t;
//    bid%8 == bc%8 keeps a stack's bands on one XCD
//  - thread owns 4 stacked rows; d=1 vertical taps from own registers
//  - temporal history (t-1, t-2) in registers -> temporal taps free
//  - NT stores: output never re-read, keep L2 for u
//  - plain __launch_bounds__(256): ",N" variants pinned VGPR and spilled
__global__ __launch_bounds__(256) void lap_st_kernel(
    const float* __restrict__ u,
    const float* __restrict__ Ds,   // (3, 64)
    const float* __restrict__ Dt,   // (2, 64)
    float* __restrict__ out)
{
    const int bid  = blockIdx.x;
    const int sh   = bid >> 8;             // 0..3 : row band
    const int bc   = bid & 255;            // b*C + c
    const int c    = bc & (CC - 1);
    const int tid  = threadIdx.x;
    const int jj   = tid >> 5;             // 0..7 : row group within band
    const int colc = tid & 31;             // chunk column (lane in row segment)
    const int col  = colc << 2;
    const int r0   = (sh << 5) + (jj << 2); // first of 4 owned rows, 0..124

    const float cs0 = softplus_f(Ds[0 * CC + c]);
    const float cs1 = softplus_f(Ds[1 * CC + c]);
    const float cs2 = softplus_f(Ds[2 * CC + c]);
    const float ct0 = softplus_f(Dt[0 * CC + c]);
    const float ct1 = softplus_f(Dt[1 * CC + c]);
    const float cu = -4.0f * (cs0 + cs1 + cs2) - (ct0 + ct1);

    const size_t bc_off = (size_t)bc * TT * HW;

    // fixed (clamped) row indices -- computed once
    const int rm1 = (r0 - 1 < 0) ? 0 : r0 - 1;
    const int rp4 = (r0 + 4 > HH - 1) ? HH - 1 : r0 + 4;
    int rA4[3], rB4[3], rA16[4], rB16[4];
    #pragma unroll
    for (int q = 0; q < 3; ++q) {
        int ru = r0 - 4 + q; rA4[q] = ru < 0 ? 0 : ru;          // vu4 for q=0,1,2
        int rd = r0 + 5 + q; rB4[q] = rd > HH - 1 ? HH - 1 : rd; // vd4 for q=1,2,3
    }
    #pragma unroll
    for (int q = 0; q < 4; ++q) {
        int ru = r0 - 16 + q; rA16[q] = ru < 0 ? 0 : ru;
        int rd = r0 + 16 + q; rB16[q] = rd > HH - 1 ? HH - 1 : rd;
    }

    float4 pm1[4], pm2[4];

    #pragma unroll 1
    for (int t = 0; t < TT; ++t) {
        const float* __restrict__ up = u + bc_off + (size_t)t * HW;
        f32x4* outp = (f32x4*)(out + bc_off + (size_t)t * HW);

        // ======== phase 1: issue ALL plane loads (20 float4) ========
        float4 c0[4], a4[3], b4[3], a16[4], b16[4], vm1, vp4;
        #pragma unroll
        for (int q = 0; q < 4; ++q)
            c0[q] = *(const float4*)(up + (r0 + q) * WW + col);
        vm1 = *(const float4*)(up + rm1 * WW + col);
        vp4 = *(const float4*)(up + rp4 * WW + col);
        #pragma unroll
        for (int q = 0; q < 3; ++q) {
            a4[q] = *(const float4*)(up + rA4[q] * WW + col);
            b4[q] = *(const float4*)(up + rB4[q] * WW + col);
        }
        #pragma unroll
        for (int q = 0; q < 4; ++q) {
            a16[q] = *(const float4*)(up + rA16[q] * WW + col);
            b16[q] = *(const float4*)(up + rB16[q] * WW + col);
        }

        if (t == 0) {   // causal clamp: u[-1] = u[-2] = u[0]
            #pragma unroll
            for (int q = 0; q < 4; ++q) { pm1[q] = c0[q]; pm2[q] = c0[q]; }
        }

        // ======== phase 2: compute all 4 rows ========
        #pragma unroll
        for (int q = 0; q < 4; ++q) {
            const int r = r0 + q;

            const float4 vu1  = (q == 0) ? vm1 : c0[q - 1];
            const float4 vd1  = (q == 3) ? vp4 : c0[q + 1];
            const float4 vu4  = (q == 3) ? vm1 : a4[q];
            const float4 vd4  = (q == 0) ? vp4 : b4[q - 1];
            const float4 vu16 = a16[q];
            const float4 vd16 = b16[q];

            const float4 cc = c0[q];

            // horizontal taps from adjacent lanes' registers
            const float4 L4  = shfl4(cc, colc - 1);
            const float4 R4  = shfl4(cc, colc + 1);
            const float4 L16 = shfl4(cc, colc - 4);
            const float4 R16 = shfl4(cc, colc + 4);
            const float e0   = __shfl(cc.x, 0, 32);    // row elem 0
            const float e127 = __shfl(cc.w, 31, 32);   // row elem 127
            const float4 l4  = (colc >= 1)  ? L4  : splat4(e0);
            const float4 r4  = (colc <= 30) ? R4  : splat4(e127);
            const float4 l16 = (colc >= 4)  ? L16 : splat4(e0);
            const float4 r16 = (colc <= 27) ? R16 : splat4(e127);

            const float4 p1 = pm1[q];
            const float4 p2 = pm2[q];

            f32x4 o;
            o.x = cs0 * (vu1.x + vd1.x + l4.w + cc.y)
                + cs1 * (vu4.x + vd4.x + l4.x + r4.x)
                + cs2 * (vu16.x + vd16.x + l16.x + r16.x)
                + cu * cc.x + ct0 * p1.x + ct1 * p2.x;
            o.y = cs0 * (vu1.y + vd1.y + cc.x + cc.z)
                + cs1 * (vu4.y + vd4.y + l4.y + r4.y)
                + cs2 * (vu16.y + vd16.y + l16.y + r16.y)
                + cu * cc.y + ct0 * p1.y + ct1 * p2.y;
            o.z = cs0 * (vu1.z + vd1.z + cc.y + cc.w)
                + cs1 * (vu4.z + vd4.z + l4.z + r4.z)
                + cs2 * (vu16.z + vd16.z + l16.z + r16.z)
                + cu * cc.z + ct0 * p1.z + ct1 * p2.z;
            o.w = cs0 * (vu1.w + vd1.w + cc.z + r4.x)
                + cs1 * (vu4.w + vd4.w + l4.w + r4.w)
                + cs2 * (vu16.w + vd16.w + l16.w + r16.w)
                + cu * cc.w + ct0 * p1.w + ct1 * p2.w;

            __builtin_nontemporal_store(o, &outp[r * 32 + colc]);
        }

        // rotate temporal history
        #pragma unroll
        for (int q = 0; q < 4; ++q) { pm2[q] = pm1[q]; pm1[q] = c0[q]; }
    }
}

extern "C" void kernel_launch(void* const* d_in, const int* in_sizes, int n_in,
                              void* d_out, int out_size, void* d_ws, size_t ws_size,
                              hipStream_t stream) {
    const float* u  = (const float*)d_in[0];
    const float* Ds = (const float*)d_in[1];
    const float* Dt = (const float*)d_in[2];
    float* out = (float*)d_out;

    const int nblocks = 4 * BB * CC;   // 1024 blocks = 4 per CU (round-11 shape)
    lap_st_kernel<<<dim3(nblocks), dim3(256), 0, stream>>>(u, Ds, Dt, out);
}

// Round 17
// 112.126 us; speedup vs baseline: 1.4754x; 1.2311x over previous
//
#include <hip/hip_runtime.h>
#include <math.h>

// Problem dims (from reference): B=4, C=64, T=16, H=128, W=128, fp32.
#define BB 4
#define CC 64
#define TT 16
#define HH 128
#define WW 128
#define HW (HH*WW)

typedef float f32x4 __attribute__((ext_vector_type(4)));

__device__ __forceinline__ float softplus_f(float x) {
    return (x > 20.0f) ? x : log1pf(expf(x));
}

__device__ __forceinline__ float4 splat4(float v) { return make_float4(v, v, v, v); }

// float4 cross-lane fetch within a 32-lane row segment (ds_bpermute x4).
// Out-of-range src wraps (&31) -> caller masks those lanes with a select.
__device__ __forceinline__ float4 shfl4(float4 v, int src) {
    float4 r;
    r.x = __shfl(v.x, src, 32);
    r.y = __shfl(v.y, src, 32);
    r.z = __shfl(v.z, src, 32);
    r.w = __shfl(v.w, src, 32);
    return r;
}

// lgkm-only barrier: orders LDS/shuffle traffic only; global loads and NT
// stores stay in flight across it (round-5 proof: vmcnt drain cost 19us).
__device__ __forceinline__ void barrier_lgkm() {
    asm volatile("s_waitcnt lgkmcnt(0)\n\ts_barrier" ::: "memory");
}

// Round-11 kernel (101us best) + ONE per-plane lgkm barrier.
// Clean A/B on a single variable. Evidence: dur tracks FETCH_SIZE in every
// round; R14 showed FETCH inflation with UNCHANGED stream count when
// waves/block doubled -> the desync is INTRA-block (per-thread t-loop, no
// sync: a block's own waves drift planes apart, widening the live u-window
// per band). This barrier t-locks the 4 waves of each 256-thread block at
// plane granularity; cost is a 4-wave lgkm-only sync (global traffic keeps
// flowing). R15 tested barrier+full-stack-block (two variables) and can't
// isolate; this isolates.
//  - 1024 blocks x 256 threads; block (sh 0..3, bc) owns rows
//    [32sh, 32sh+32) of stack bc for all t; bid%8==bc%8 -> bands on one XCD
//  - NO LDS buffers; horizontal taps via lane shuffles (round-11 win)
//  - thread owns 4 stacked rows: d=1 vertical taps from own registers
//  - temporal history (t-1, t-2) in registers -> temporal taps free
//  - interleaved per-row load/compute schedule (round-16 batching regressed)
//  - NT stores: output never re-read, keep L2/L3 for u
//  - plain __launch_bounds__(256): ",N" variants pinned VGPR and spilled
__global__ __launch_bounds__(256) void lap_st_kernel(
    const float* __restrict__ u,
    const float* __restrict__ Ds,   // (3, 64)
    const float* __restrict__ Dt,   // (2, 64)
    float* __restrict__ out)
{
    const int bid  = blockIdx.x;
    const int sh   = bid >> 8;             // 0..3 : row band
    const int bc   = bid & 255;            // b*C + c
    const int c    = bc & (CC - 1);
    const int tid  = threadIdx.x;
    const int jj   = tid >> 5;             // 0..7 : row group within band
    const int colc = tid & 31;             // chunk column (lane in row segment)
    const int col  = colc << 2;
    const int r0   = (sh << 5) + (jj << 2); // first of 4 owned rows, 0..124

    const float cs0 = softplus_f(Ds[0 * CC + c]);
    const float cs1 = softplus_f(Ds[1 * CC + c]);
    const float cs2 = softplus_f(Ds[2 * CC + c]);
    const float ct0 = softplus_f(Dt[0 * CC + c]);
    const float ct1 = softplus_f(Dt[1 * CC + c]);
    const float cu = -4.0f * (cs0 + cs1 + cs2) - (ct0 + ct1);

    const size_t bc_off = (size_t)bc * TT * HW;

    float4 pm1[4], pm2[4];

    #pragma unroll 1
    for (int t = 0; t < TT; ++t) {
        const float* __restrict__ up = u + bc_off + (size_t)t * HW;
        f32x4* outp = (f32x4*)(out + bc_off + (size_t)t * HW);

        // t-lock the block's 4 waves: keeps the band's live u-window at
        // ~1 plane so spatial taps stay cache-resident
        barrier_lgkm();

        // center rows (registers; feed +-1 taps, horizontals via shuffle,
        // and the temporal rotate)
        float4 c0[4];
        #pragma unroll
        for (int q = 0; q < 4; ++q)
            c0[q] = *(const float4*)(up + (r0 + q) * WW + col);

        if (t == 0) {   // causal clamp: u[-1] = u[-2] = u[0]
            #pragma unroll
            for (int q = 0; q < 4; ++q) { pm1[q] = c0[q]; pm2[q] = c0[q]; }
        }

        // shared boundary rows (serve +-1 taps of edge q and +-4 taps)
        const int rm1 = (r0 - 1 < 0) ? 0 : r0 - 1;
        const int rp4 = (r0 + 4 > HH - 1) ? HH - 1 : r0 + 4;
        const float4 vm1 = *(const float4*)(up + rm1 * WW + col);
        const float4 vp4 = *(const float4*)(up + rp4 * WW + col);

        #pragma unroll
        for (int q = 0; q < 4; ++q) {
            const int r = r0 + q;

            // ---- vertical taps (register reuse for d=1; clamped loads) ----
            const float4 vu1 = (q == 0) ? vm1 : c0[q - 1];
            const float4 vd1 = (q == 3) ? vp4 : c0[q + 1];
            float4 vu4, vd4;
            if (q == 3) vu4 = vm1;                       // r-4 == r0-1
            else { int rr = r - 4; rr = rr < 0 ? 0 : rr;
                   vu4 = *(const float4*)(up + rr * WW + col); }
            if (q == 0) vd4 = vp4;                       // r+4 == r0+4
            else { int rr = r + 4; rr = rr > HH - 1 ? HH - 1 : rr;
                   vd4 = *(const float4*)(up + rr * WW + col); }
            int ru16 = r - 16; ru16 = ru16 < 0 ? 0 : ru16;
            int rd16 = r + 16; rd16 = rd16 > HH - 1 ? HH - 1 : rd16;
            const float4 vu16 = *(const float4*)(up + ru16 * WW + col);
            const float4 vd16 = *(const float4*)(up + rd16 * WW + col);

            const float4 cc = c0[q];

            // ---- horizontal taps from adjacent lanes' registers ----
            const float4 L4  = shfl4(cc, colc - 1);
            const float4 R4  = shfl4(cc, colc + 1);
            const float4 L16 = shfl4(cc, colc - 4);
            const float4 R16 = shfl4(cc, colc + 4);
            const float e0   = __shfl(cc.x, 0, 32);    // row elem 0
            const float e127 = __shfl(cc.w, 31, 32);   // row elem 127
            const float4 l4  = (colc >= 1)  ? L4  : splat4(e0);
            const float4 r4  = (colc <= 30) ? R4  : splat4(e127);
            const float4 l16 = (colc >= 4)  ? L16 : splat4(e0);
            const float4 r16 = (colc <= 27) ? R16 : splat4(e127);

            const float4 p1 = pm1[q];
            const float4 p2 = pm2[q];

            f32x4 o;
            o.x = cs0 * (vu1.x + vd1.x + l4.w + cc.y)
                + cs1 * (vu4.x + vd4.x + l4.x + r4.x)
                + cs2 * (vu16.x + vd16.x + l16.x + r16.x)
                + cu * cc.x + ct0 * p1.x + ct1 * p2.x;
            o.y = cs0 * (vu1.y + vd1.y + cc.x + cc.z)
                + cs1 * (vu4.y + vd4.y + l4.y + r4.y)
                + cs2 * (vu16.y + vd16.y + l16.y + r16.y)
                + cu * cc.y + ct0 * p1.y + ct1 * p2.y;
            o.z = cs0 * (vu1.z + vd1.z + cc.y + cc.w)
                + cs1 * (vu4.z + vd4.z + l4.z + r4.z)
                + cs2 * (vu16.z + vd16.z + l16.z + r16.z)
                + cu * cc.z + ct0 * p1.z + ct1 * p2.z;
            o.w = cs0 * (vu1.w + vd1.w + cc.z + r4.x)
                + cs1 * (vu4.w + vd4.w + l4.w + r4.w)
                + cs2 * (vu16.w + vd16.w + l16.w + r16.w)
                + cu * cc.w + ct0 * p1.w + ct1 * p2.w;

            __builtin_nontemporal_store(o, &outp[r * 32 + colc]);
        }

        // rotate temporal history
        #pragma unroll
        for (int q = 0; q < 4; ++q) { pm2[q] = pm1[q]; pm1[q] = c0[q]; }
    }
}

extern "C" void kernel_launch(void* const* d_in, const int* in_sizes, int n_in,
                              void* d_out, int out_size, void* d_ws, size_t ws_size,
                              hipStream_t stream) {
    const float* u  = (const float*)d_in[0];
    const float* Ds = (const float*)d_in[1];
    const float* Dt = (const float*)d_in[2];
    float* out = (float*)d_out;

    const int nblocks = 4 * BB * CC;   // 1024 blocks = 4 per CU (round-11 shape)
    lap_st_kernel<<<dim3(nblocks), dim3(256), 0, stream>>>(u, Ds, Dt, out);
}

// Round 18
// 110.796 us; speedup vs baseline: 1.4931x; 1.0120x over previous
//
#include <hip/hip_runtime.h>
#include <math.h>

// Problem dims (from reference): B=4, C=64, T=16, H=128, W=128, fp32.
#define BB 4
#define CC 64
#define TT 16
#define HH 128
#define WW 128
#define HW (HH*WW)
#define PW 128              // LDS row stride (floats); linear, no pad (b128 lane pattern is conflict-free)

typedef float f32x4 __attribute__((ext_vector_type(4)));

__device__ __forceinline__ float softplus_f(float x) {
    return (x > 20.0f) ? x : log1pf(expf(x));
}

__device__ __forceinline__ float4 splat4(float v) { return make_float4(v, v, v, v); }

// float4 cross-lane fetch within a 32-lane row segment (ds_bpermute x4).
__device__ __forceinline__ float4 shfl4(float4 v, int src) {
    float4 r;
    r.x = __shfl(v.x, src, 32);
    r.y = __shfl(v.y, src, 32);
    r.z = __shfl(v.z, src, 32);
    r.w = __shfl(v.w, src, 32);
    return r;
}

// Async DMA-staged stencil (T3/T4 pattern): 256 blocks x 1024 threads
// (1/CU), ping-pong 2x64KB LDS plane buffers. Per plane:
//   issue global_load_lds(plane t+1 -> bufB)   [async, no VGPR roundtrip]
//   compute plane t from bufA: vertical taps = ds_read_b128 (zero L1/L2
//     traffic, zero latency exposure), horizontal taps = lane shuffles,
//     temporal taps = registers; NT-store out
//   s_waitcnt vmcnt(4) + s_barrier; swap.
// vmcnt(4) counts this iter's 4 NT stores: in-order retirement means the
// 4 OLDER stage loads have retired -- never vmcnt(0), stores keep
// streaming (AITER counted-wait idiom). This decouples HBM latency from
// wave count: rounds 11-17 showed the cache-tap kernel is latency-bound
// (VALUBusy 18%) and every TLP increase inflated FETCH; here waves are
// stall-free during compute and the DMA engine feeds HBM.
// Budget/plane/CU: HBM 128KB = 12.8Kcyc; LDS reads ~458KB = ~4-7Kcyc;
// VALU ~2Kcyc -> HBM-bound ~85us floor.
__global__ __launch_bounds__(1024) void lap_st_kernel(
    const float* __restrict__ u,
    const float* __restrict__ Ds,   // (3, 64)
    const float* __restrict__ Dt,   // (2, 64)
    float* __restrict__ out)
{
    __shared__ __align__(16) float sm[2 * HH * PW];   // 131072 B

    const int bc   = blockIdx.x;           // b*C + c (stack id)
    const int c    = bc & (CC - 1);
    const int tid  = threadIdx.x;
    const int colc = tid & 31;             // chunk column (lane in 32-lane row segment)

    const float cs0 = softplus_f(Ds[0 * CC + c]);
    const float cs1 = softplus_f(Ds[1 * CC + c]);
    const float cs2 = softplus_f(Ds[2 * CC + c]);
    const float ct0 = softplus_f(Dt[0 * CC + c]);
    const float ct1 = softplus_f(Dt[1 * CC + c]);
    const float cu = -4.0f * (cs0 + cs1 + cs2) - (ct0 + ct1);

    const size_t bc_off = (size_t)bc * TT * HW;
    const int kwb = tid & ~63;             // wave-uniform chunk base within a 1024-chunk slab

    // ---- prologue: DMA-stage plane 0 into buffer 0 ----
    {
        const float* p0 = u + bc_off;
        #pragma unroll
        for (int i = 0; i < 4; ++i) {
            const int k  = tid + (i << 10);        // this lane's chunk
            const int kb = kwb + (i << 10);        // wave-uniform base chunk
            __builtin_amdgcn_global_load_lds(
                (const __attribute__((address_space(1))) void*)(p0 + ((size_t)k << 2)),
                (__attribute__((address_space(3))) void*)(sm + (kb << 2)),
                16, 0, 0);
        }
    }
    asm volatile("s_waitcnt vmcnt(0)\n\ts_barrier" ::: "memory");

    float4 pm1[4], pm2[4];

    #pragma unroll 1
    for (int t = 0; t < TT; ++t) {
        const float* __restrict__ smA = sm + (t & 1) * (HH * PW);       // plane t (read)
        float*       __restrict__ smB = sm + ((t + 1) & 1) * (HH * PW); // plane t+1 (DMA dst)
        f32x4* outp = (f32x4*)(out + bc_off + (size_t)t * HW);

        // ---- issue async stage of plane t+1 (completes during compute) ----
        if (t < TT - 1) {
            const float* pn = u + bc_off + (size_t)(t + 1) * HW;
            #pragma unroll
            for (int i = 0; i < 4; ++i) {
                const int k  = tid + (i << 10);
                const int kb = kwb + (i << 10);
                __builtin_amdgcn_global_load_lds(
                    (const __attribute__((address_space(1))) void*)(pn + ((size_t)k << 2)),
                    (__attribute__((address_space(3))) void*)(smB + (kb << 2)),
                    16, 0, 0);
            }
        }

        // ---- compute plane t from smA (LDS taps; no global reads) ----
        float4 c0[4];
        #pragma unroll
        for (int i = 0; i < 4; ++i) {
            const int k   = tid + (i << 10);
            const int row = k >> 5;
            const int col = colc << 2;

            const float4 cc = *(const float4*)&smA[row * PW + col];
            c0[i] = cc;

            const int rU1  = (row >= 1)       ? row - 1  : 0;
            const int rD1  = (row <= HH - 2)  ? row + 1  : HH - 1;
            const int rU4  = (row >= 4)       ? row - 4  : 0;
            const int rD4  = (row <= HH - 5)  ? row + 4  : HH - 1;
            const int rU16 = (row >= 16)      ? row - 16 : 0;
            const int rD16 = (row <= HH - 17) ? row + 16 : HH - 1;

            const float4 vu1  = *(const float4*)&smA[rU1  * PW + col];
            const float4 vd1  = *(const float4*)&smA[rD1  * PW + col];
            const float4 vu4  = *(const float4*)&smA[rU4  * PW + col];
            const float4 vd4  = *(const float4*)&smA[rD4  * PW + col];
            const float4 vu16 = *(const float4*)&smA[rU16 * PW + col];
            const float4 vd16 = *(const float4*)&smA[rD16 * PW + col];

            // horizontal taps from adjacent lanes' registers
            const float4 L4  = shfl4(cc, colc - 1);
            const float4 R4  = shfl4(cc, colc + 1);
            const float4 L16 = shfl4(cc, colc - 4);
            const float4 R16 = shfl4(cc, colc + 4);
            const float e0   = __shfl(cc.x, 0, 32);    // row elem 0
            const float e127 = __shfl(cc.w, 31, 32);   // row elem 127
            const float4 l4  = (colc >= 1)  ? L4  : splat4(e0);
            const float4 r4  = (colc <= 30) ? R4  : splat4(e127);
            const float4 l16 = (colc >= 4)  ? L16 : splat4(e0);
            const float4 r16 = (colc <= 27) ? R16 : splat4(e127);

            const float4 p1 = (t == 0) ? cc : pm1[i];
            const float4 p2 = (t == 0) ? cc : pm2[i];

            f32x4 o;
            o.x = cs0 * (vu1.x + vd1.x + l4.w + cc.y)
                + cs1 * (vu4.x + vd4.x + l4.x + r4.x)
                + cs2 * (vu16.x + vd16.x + l16.x + r16.x)
                + cu * cc.x + ct0 * p1.x + ct1 * p2.x;
            o.y = cs0 * (vu1.y + vd1.y + cc.x + cc.z)
                + cs1 * (vu4.y + vd4.y + l4.y + r4.y)
                + cs2 * (vu16.y + vd16.y + l16.y + r16.y)
                + cu * cc.y + ct0 * p1.y + ct1 * p2.y;
            o.z = cs0 * (vu1.z + vd1.z + cc.y + cc.w)
                + cs1 * (vu4.z + vd4.z + l4.z + r4.z)
                + cs2 * (vu16.z + vd16.z + l16.z + r16.z)
                + cu * cc.z + ct0 * p1.z + ct1 * p2.z;
            o.w = cs0 * (vu1.w + vd1.w + cc.z + r4.x)
                + cs1 * (vu4.w + vd4.w + l4.w + r4.w)
                + cs2 * (vu16.w + vd16.w + l16.w + r16.w)
                + cu * cc.w + ct0 * p1.w + ct1 * p2.w;

            __builtin_nontemporal_store(o, &outp[k]);   // streaming, never re-read
        }

        // rotate temporal history (registers only)
        #pragma unroll
        for (int i = 0; i < 4; ++i) {
            pm2[i] = (t == 0) ? c0[i] : pm1[i];
            pm1[i] = c0[i];
        }

        // counted wait: outstanding <= 4 (this iter's 4 NT stores) ==>
        // the 4 older stage loads of plane t+1 have retired. Then barrier.
        // Never vmcnt(0): stores stream on, reads never drain.
        if (t < TT - 1)
            asm volatile("s_waitcnt vmcnt(4) lgkmcnt(0)\n\ts_barrier" ::: "memory");
    }
}

extern "C" void kernel_launch(void* const* d_in, const int* in_sizes, int n_in,
                              void* d_out, int out_size, void* d_ws, size_t ws_size,
                              hipStream_t stream) {
    const float* u  = (const float*)d_in[0];
    const float* Ds = (const float*)d_in[1];
    const float* Dt = (const float*)d_in[2];
    float* out = (float*)d_out;

    const int nblocks = BB * CC;   // 256 -> one stack per block, one block per CU
    lap_st_kernel<<<dim3(nblocks), dim3(1024), 0, stream>>>(u, Ds, Dt, out);
}

// Round 19
// 99.001 us; speedup vs baseline: 1.6710x; 1.1191x over previous
//
#include <hip/hip_runtime.h>
#include <math.h>

// Problem dims (from reference): B=4, C=64, T=16, H=128, W=128, fp32.
#define BB 4
#define CC 64
#define TT 16
#define HH 128
#define WW 128
#define HW (HH*WW)

typedef float f32x4 __attribute__((ext_vector_type(4)));

__device__ __forceinline__ float softplus_f(float x) {
    return (x > 20.0f) ? x : log1pf(expf(x));
}

__device__ __forceinline__ float4 splat4(float v) { return make_float4(v, v, v, v); }

// float4 cross-lane fetch within a 32-lane row segment (ds_bpermute x4).
__device__ __forceinline__ float4 shfl4(float4 v, int src) {
    float4 r;
    r.x = __shfl(v.x, src, 32);
    r.y = __shfl(v.y, src, 32);
    r.z = __shfl(v.z, src, 32);
    r.w = __shfl(v.w, src, 32);
    return r;
}

// R11 body EXACTLY (101us best: 4-row threads, shuffle horizontals, cache
// vertical taps, register temporal history, NT stores, free-running waves)
// with 64-ROW BANDS: 512 blocks x 512 threads (2 blocks/CU x 8 waves = 16
// waves/CU, SAME wave count as R11's 4x4). Mechanism: R11's d=+-16 taps
// reach 16 rows into each neighbor band -> every plane-row feeds 2 blocks'
// tap streams (2x read amplification into L3; u=268MB > L3=256MB spills
// the excess to HBM = the warm 164MB FETCH). 64-row bands cut the
// halo/owned ratio to 1.5x and halve the stream count; dur has tracked
// FETCH in rounds 11-17, so less amplification => less dur.
// R14 regressed by doubling waves/CU (32) with unchanged bands -- this
// keeps waves fixed and isolates band size.
//  - NO LDS, NO barriers, NO prefetch, NO batching (all 8 variants of
//    those regressed in rounds 12-18)
//  - bid = sh*256 + bc, 256%8==0 -> bid%8 == bc%8: a stack's 2 bands stay
//    on one XCD for L2 halo sharing
//  - plain __launch_bounds__(512): ",N" variants pinned VGPR and spilled
__global__ __launch_bounds__(512) void lap_st_kernel(
    const float* __restrict__ u,
    const float* __restrict__ Ds,   // (3, 64)
    const float* __restrict__ Dt,   // (2, 64)
    float* __restrict__ out)
{
    const int bid  = blockIdx.x;
    const int sh   = bid >> 8;             // 0..1 : 64-row band
    const int bc   = bid & 255;            // b*C + c
    const int c    = bc & (CC - 1);
    const int tid  = threadIdx.x;
    const int jj   = tid >> 5;             // 0..15 : row group within band
    const int colc = tid & 31;             // chunk column (lane in row segment)
    const int col  = colc << 2;
    const int r0   = (sh << 6) + (jj << 2); // first of 4 owned rows, 0..124

    const float cs0 = softplus_f(Ds[0 * CC + c]);
    const float cs1 = softplus_f(Ds[1 * CC + c]);
    const float cs2 = softplus_f(Ds[2 * CC + c]);
    const float ct0 = softplus_f(Dt[0 * CC + c]);
    const float ct1 = softplus_f(Dt[1 * CC + c]);
    const float cu = -4.0f * (cs0 + cs1 + cs2) - (ct0 + ct1);

    const size_t bc_off = (size_t)bc * TT * HW;

    float4 pm1[4], pm2[4];

    #pragma unroll 1
    for (int t = 0; t < TT; ++t) {
        const float* __restrict__ up = u + bc_off + (size_t)t * HW;
        f32x4* outp = (f32x4*)(out + bc_off + (size_t)t * HW);

        // center rows (registers; feed +-1 taps, horizontals via shuffle,
        // and the temporal rotate)
        float4 c0[4];
        #pragma unroll
        for (int q = 0; q < 4; ++q)
            c0[q] = *(const float4*)(up + (r0 + q) * WW + col);

        if (t == 0) {   // causal clamp: u[-1] = u[-2] = u[0]
            #pragma unroll
            for (int q = 0; q < 4; ++q) { pm1[q] = c0[q]; pm2[q] = c0[q]; }
        }

        // shared boundary rows (serve +-1 taps of edge q and +-4 taps)
        const int rm1 = (r0 - 1 < 0) ? 0 : r0 - 1;
        const int rp4 = (r0 + 4 > HH - 1) ? HH - 1 : r0 + 4;
        const float4 vm1 = *(const float4*)(up + rm1 * WW + col);
        const float4 vp4 = *(const float4*)(up + rp4 * WW + col);

        #pragma unroll
        for (int q = 0; q < 4; ++q) {
            const int r = r0 + q;

            // ---- vertical taps (register reuse for d=1; clamped loads) ----
            const float4 vu1 = (q == 0) ? vm1 : c0[q - 1];
            const float4 vd1 = (q == 3) ? vp4 : c0[q + 1];
            float4 vu4, vd4;
            if (q == 3) vu4 = vm1;                       // r-4 == r0-1
            else { int rr = r - 4; rr = rr < 0 ? 0 : rr;
                   vu4 = *(const float4*)(up + rr * WW + col); }
            if (q == 0) vd4 = vp4;                       // r+4 == r0+4
            else { int rr = r + 4; rr = rr > HH - 1 ? HH - 1 : rr;
                   vd4 = *(const float4*)(up + rr * WW + col); }
            int ru16 = r - 16; ru16 = ru16 < 0 ? 0 : ru16;
            int rd16 = r + 16; rd16 = rd16 > HH - 1 ? HH - 1 : rd16;
            const float4 vu16 = *(const float4*)(up + ru16 * WW + col);
            const float4 vd16 = *(const float4*)(up + rd16 * WW + col);

            const float4 cc = c0[q];

            // ---- horizontal taps from adjacent lanes' registers ----
            const float4 L4  = shfl4(cc, colc - 1);
            const float4 R4  = shfl4(cc, colc + 1);
            const float4 L16 = shfl4(cc, colc - 4);
            const float4 R16 = shfl4(cc, colc + 4);
            const float e0   = __shfl(cc.x, 0, 32);    // row elem 0
            const float e127 = __shfl(cc.w, 31, 32);   // row elem 127
            const float4 l4  = (colc >= 1)  ? L4  : splat4(e0);
            const float4 r4  = (colc <= 30) ? R4  : splat4(e127);
            const float4 l16 = (colc >= 4)  ? L16 : splat4(e0);
            const float4 r16 = (colc <= 27) ? R16 : splat4(e127);

            const float4 p1 = pm1[q];
            const float4 p2 = pm2[q];

            f32x4 o;
            o.x = cs0 * (vu1.x + vd1.x + l4.w + cc.y)
                + cs1 * (vu4.x + vd4.x + l4.x + r4.x)
                + cs2 * (vu16.x + vd16.x + l16.x + r16.x)
                + cu * cc.x + ct0 * p1.x + ct1 * p2.x;
            o.y = cs0 * (vu1.y + vd1.y + cc.x + cc.z)
                + cs1 * (vu4.y + vd4.y + l4.y + r4.y)
                + cs2 * (vu16.y + vd16.y + l16.y + r16.y)
                + cu * cc.y + ct0 * p1.y + ct1 * p2.y;
            o.z = cs0 * (vu1.z + vd1.z + cc.y + cc.w)
                + cs1 * (vu4.z + vd4.z + l4.z + r4.z)
                + cs2 * (vu16.z + vd16.z + l16.z + r16.z)
                + cu * cc.z + ct0 * p1.z + ct1 * p2.z;
            o.w = cs0 * (vu1.w + vd1.w + cc.z + r4.x)
                + cs1 * (vu4.w + vd4.w + l4.w + r4.w)
                + cs2 * (vu16.w + vd16.w + l16.w + r16.w)
                + cu * cc.w + ct0 * p1.w + ct1 * p2.w;

            __builtin_nontemporal_store(o, &outp[r * 32 + colc]);
        }

        // rotate temporal history
        #pragma unroll
        for (int q = 0; q < 4; ++q) { pm2[q] = pm1[q]; pm1[q] = c0[q]; }
    }
}

extern "C" void kernel_launch(void* const* d_in, const int* in_sizes, int n_in,
                              void* d_out, int out_size, void* d_ws, size_t ws_size,
                              hipStream_t stream) {
    const float* u  = (const float*)d_in[0];
    const float* Ds = (const float*)d_in[1];
    const float* Dt = (const float*)d_in[2];
    float* out = (float*)d_out;

    const int nblocks = 2 * BB * CC;   // 512 blocks x 512 threads = 2 blocks/CU
    lap_st_kernel<<<dim3(nblocks), dim3(512), 0, stream>>>(u, Ds, Dt, out);
}